// Round 5
// baseline (452.325 us; speedup 1.0000x reference)
//
#include <hip/hip_runtime.h>
#include <math.h>

#define NT 256

typedef unsigned short u16;
typedef unsigned int u32;
typedef _Float16 f16;
typedef __attribute__((ext_vector_type(2))) unsigned int u32x2;
typedef __attribute__((ext_vector_type(4))) unsigned int u32x4;
typedef __attribute__((ext_vector_type(4))) float f32x4;
typedef __attribute__((ext_vector_type(8))) short s16x8;
typedef __attribute__((ext_vector_type(8))) _Float16 f16x8;

namespace {

__device__ const float c_elev[32] = {
  -30.67f,-29.33f,-28.0f,-26.66f,-25.33f,-24.0f,-22.67f,-21.33f,
  -20.0f,-18.67f,-17.33f,-16.0f,-14.67f,-13.33f,-12.0f,-10.67f,
  -9.33f,-8.0f,-6.66f,-5.33f,-4.0f,-2.67f,-1.33f,0.0f,1.33f,
  2.67f,4.0f,5.33f,6.67f,8.0f,9.33f,10.67f };

__device__ __forceinline__ float gelu_f(float x) {
  return 0.5f * x * (1.0f + erff(x * 0.70710678118654752440f));
}
__device__ __forceinline__ u16 bf16rne(float f) {
  u32 u = __builtin_bit_cast(u32, f);
  u32 r = u + 0x7FFFu + ((u >> 16) & 1u);
  return (u16)(r >> 16);
}
__device__ __forceinline__ float bf2f(u16 h) {
  u32 u = ((u32)h) << 16;
  return __builtin_bit_cast(float, u);
}
__device__ __forceinline__ float bflo(u32 v) {       // low bf16 of packed pair
  return __builtin_bit_cast(float, v << 16);
}
__device__ __forceinline__ float bfhi(u32 v) {       // high bf16 of packed pair
  return __builtin_bit_cast(float, v & 0xFFFF0000u);
}
// split-f16 pack: u32 = f16(x) | f16(x - f16(x)) << 16
__device__ __forceinline__ u32 packsplit(float x) {
  f16 h = (f16)x;
  f16 l = (f16)(x - (float)h);
  return (u32)__builtin_bit_cast(u16, h) | ((u32)__builtin_bit_cast(u16, l) << 16);
}
__device__ __forceinline__ void unpack16(u32x4 a, u32x4 b, f16x8& hi, f16x8& lo) {
  u32x4 h, l;
  h[0] = (a[0] & 0xFFFFu) | (a[1] << 16);  l[0] = (a[0] >> 16) | (a[1] & 0xFFFF0000u);
  h[1] = (a[2] & 0xFFFFu) | (a[3] << 16);  l[1] = (a[2] >> 16) | (a[3] & 0xFFFF0000u);
  h[2] = (b[0] & 0xFFFFu) | (b[1] << 16);  l[2] = (b[0] >> 16) | (b[1] & 0xFFFF0000u);
  h[3] = (b[2] & 0xFFFFu) | (b[3] << 16);  l[3] = (b[2] >> 16) | (b[3] & 0xFFFF0000u);
  hi = __builtin_bit_cast(f16x8, h);
  lo = __builtin_bit_cast(f16x8, l);
}

// ============ split-f16 MFMA linear for the depth path (16384 rows) ============
template<int COREAL, int CO, int KPAD, int CI, int PROD, int AMODE, bool DOGELU, bool OBF>
__global__ __launch_bounds__(NT)
void slin(const float* __restrict__ Af, const float* __restrict__ A2,
          const u32* __restrict__ Wp, const float* __restrict__ bias,
          float* __restrict__ outF, u16* __restrict__ outB)
{
  constexpr int BM = 64;
  constexpr int NFR = CO / 16;
  constexpr int KS = KPAD / 32;
  __shared__ u32 lds[BM * KPAD];
  const int tid = threadIdx.x;
  const long row0 = (long)blockIdx.x * BM;

  for (int i = tid; i < BM * (KPAD / 4); i += NT) {
    int r = i / (KPAD / 4), c = (i % (KPAD / 4)) * 4;
    long pix = row0 + r;
    u32x4 o;
    if constexpr (AMODE == 0) {
      if (c + 3 < CI) {
        f32x4 v = *(const f32x4*)(Af + pix * CI + c);
#pragma unroll
        for (int e = 0; e < 4; e++) o[e] = packsplit(v[e]);
      } else {
#pragma unroll
        for (int e = 0; e < 4; e++) {
          int cc = c + e;
          o[e] = packsplit(cc < CI ? Af[pix * CI + cc] : 0.f);
        }
      }
    } else {
      if (c + 3 < 64) {
        f32x4 v = *(const f32x4*)(Af + pix * 64 + c);
#pragma unroll
        for (int e = 0; e < 4; e++) o[e] = packsplit(v[e]);
      } else {
#pragma unroll
        for (int e = 0; e < 4; e++) {
          int cc = c + e;
          float x = (cc < 64) ? Af[pix * 64 + cc] : ((cc < 67) ? A2[pix * 3 + cc - 64] : 0.f);
          o[e] = packsplit(x);
        }
      }
    }
    *(u32x4*)((char*)lds + (((r * KPAD + c) * 4) ^ ((r & 7) << 4))) = o;
  }
  __syncthreads();

  const int wave = tid >> 6, lane = tid & 63;
  const int mb = wave * 16;
  const int lr = lane & 15, kq = lane >> 4;

  f32x4 acc[NFR] = {};
#pragma unroll
  for (int ks = 0; ks < KS; ks++) {
    const int arow = mb + lr;
    const u32 sw = (arow & 7) << 4;
    const int base = arow * KPAD * 4 + ks * 128 + kq * 32;
    u32x4 a0 = *(const u32x4*)((char*)lds + (base ^ sw));
    u32x4 a1 = *(const u32x4*)((char*)lds + ((base + 16) ^ sw));
    f16x8 ah, al;
    unpack16(a0, a1, ah, al);
#pragma unroll
    for (int nf = 0; nf < NFR; nf++) {
      const u32* wp = Wp + (nf * 16 + lr) * KPAD + ks * 32 + kq * 8;
      u32x4 w0 = *(const u32x4*)wp;
      u32x4 w1 = *(const u32x4*)(wp + 4);
      f16x8 wh, wl;
      unpack16(w0, w1, wh, wl);
      acc[nf] = __builtin_amdgcn_mfma_f32_16x16x32_f16(ah, wh, acc[nf], 0, 0, 0);
      if constexpr (PROD == 3) {
        acc[nf] = __builtin_amdgcn_mfma_f32_16x16x32_f16(ah, wl, acc[nf], 0, 0, 0);
        acc[nf] = __builtin_amdgcn_mfma_f32_16x16x32_f16(al, wh, acc[nf], 0, 0, 0);
      }
    }
  }

#pragma unroll
  for (int nf = 0; nf < NFR; nf++) {
    int col = nf * 16 + lr;
    if (col >= COREAL) continue;
    float bcol = bias[col];
#pragma unroll
    for (int r = 0; r < 4; r++) {
      long row = row0 + mb + kq * 4 + r;
      float val = acc[nf][r] + bcol;
      if constexpr (DOGELU) val = gelu_f(val);
      if constexpr (OBF) outB[row * COREAL + col] = bf16rne(val);
      else               outF[row * COREAL + col] = val;
    }
  }
}

// ============ 3x3 circular conv 128->64 via split-f16 implicit-GEMM MFMA ============
__global__ __launch_bounds__(NT)
void conv_mfma(const float* __restrict__ X, const u32* __restrict__ Wc,
               float* __restrict__ Y)
{
  __shared__ u32 lds[4 * 18 * 128];
  const int tid = threadIdx.x;
  const int bRow = (blockIdx.x >> 5) * 2;
  const int bCol = (blockIdx.x & 31) * 16;

  for (int i = tid; i < 4 * 18 * 32; i += NT) {
    int c4 = (i & 31) * 4;
    int col = (i >> 5) % 18;
    int row = i / (18 * 32);
    int gy = (bRow + row - 1 + 32) & 31;
    int gx = (bCol + col - 1 + 512) & 511;
    f32x4 v = *(const f32x4*)(X + ((long)gy * 512 + gx) * 128 + c4);
    u32x4 o;
#pragma unroll
    for (int e = 0; e < 4; e++) o[e] = packsplit(v[e]);
    *(u32x4*)((char*)lds + ((((row * 18 + col) * 128 + c4) * 4) ^ ((col & 7) << 4))) = o;
  }
  __syncthreads();

  const int wave = tid >> 6, lane = tid & 63;
  const int wm = wave >> 1;
  const int nb = (wave & 1) * 32;
  const int lr = lane & 15, kq = lane >> 4;

  f32x4 acc[2] = {};
  for (int t = 0; t < 9; t++) {
    const int ky = t / 3, kx = t % 3;
    const int wrow = wm + ky;
    const int wcol = lr + kx;
    const u32 sw = (wcol & 7) << 4;
    const int rowbase = (wrow * 18 + wcol) * 512;
#pragma unroll
    for (int ks = 0; ks < 4; ks++) {
      const int base = rowbase + ks * 128 + kq * 32;
      u32x4 a0 = *(const u32x4*)((char*)lds + (base ^ sw));
      u32x4 a1 = *(const u32x4*)((char*)lds + ((base + 16) ^ sw));
      f16x8 ah, al;
      unpack16(a0, a1, ah, al);
#pragma unroll
      for (int nf = 0; nf < 2; nf++) {
        const u32* wp = Wc + ((t * 64 + nb + nf * 16 + lr) * 128 + ks * 32 + kq * 8);
        u32x4 w0 = *(const u32x4*)wp;
        u32x4 w1 = *(const u32x4*)(wp + 4);
        f16x8 wh, wl;
        unpack16(w0, w1, wh, wl);
        acc[nf] = __builtin_amdgcn_mfma_f32_16x16x32_f16(ah, wh, acc[nf], 0, 0, 0);
        acc[nf] = __builtin_amdgcn_mfma_f32_16x16x32_f16(ah, wl, acc[nf], 0, 0, 0);
        acc[nf] = __builtin_amdgcn_mfma_f32_16x16x32_f16(al, wh, acc[nf], 0, 0, 0);
      }
    }
  }

  const int gy = bRow + wm;
#pragma unroll
  for (int nf = 0; nf < 2; nf++) {
    int co = nb + nf * 16 + lr;
#pragma unroll
    for (int r = 0; r < 4; r++) {
      int gx = bCol + kq * 4 + r;
      Y[((long)gy * 512 + gx) * 64 + co] = acc[nf][r];
    }
  }
}

// ================= bf16 MFMA linear (smooth path), K=128, BM=64, 4 waves =================
// AMODE: 0 = bf16 row-major A [N][128]; 1 = bf16 row-dup (row -> A[row/5]); 4 = f32 col-major
// SPLIT: CO=160 merged off(f32,96)/aw(bf16,48) output
template<int CO, int AMODE, bool DEPTH, bool DOGELU, bool WF, bool WBF, bool SPLIT>
__global__ __launch_bounds__(NT)
void mfma_lin(const void* __restrict__ Ap, const float* __restrict__ A2,
              const u16* __restrict__ Wb, const float* __restrict__ bias,
              const float* __restrict__ extraW,
              float* __restrict__ outF, u16* __restrict__ outB, int ldA)
{
  constexpr int BM = 64;
  __shared__ u32x4 smem[(BM + CO) * 16];
  char* As = (char*)smem;
  char* Bs = (char*)smem + BM * 256;
  const int tid = threadIdx.x;
  const long row0 = (long)blockIdx.x * BM;

  for (int i = tid; i < CO * 16; i += NT) {
    int r = i >> 4, ck = i & 15;
    u32x4 v = ((const u32x4*)(Wb + r * 128))[ck];
    *(u32x4*)(Bs + ((r * 256 + ck * 16) ^ ((r & 7) << 4))) = v;
  }
  if constexpr (AMODE == 0 || AMODE == 1) {
    const u16* A = (const u16*)Ap;
    for (int i = tid; i < BM * 16; i += NT) {
      int r = i >> 4, ck = i & 15;
      long src = (AMODE == 1) ? ((row0 + r) / 5) : (row0 + r);
      u32x4 v = ((const u32x4*)(A + src * 128))[ck];
      *(u32x4*)(As + ((r * 256 + ck * 16) ^ ((r & 7) << 4))) = v;
    }
  } else if constexpr (AMODE == 4) {
    const float* A = (const float*)Ap;
    for (int i = tid; i < 128 * 16; i += NT) {
      int k = i >> 4, rg = i & 15;
      f32x4 v = *(const f32x4*)(A + (long)k * ldA + row0 + rg * 4);
#pragma unroll
      for (int e = 0; e < 4; e++) {
        int r = rg * 4 + e;
        *(u16*)(As + ((r * 256 + k * 2) ^ ((r & 7) << 4))) = bf16rne(v[e]);
      }
    }
  }
  __syncthreads();

  constexpr int WROWS = (CO >= 96) ? 2 : 4;
  constexpr int WCOLS = 4 / WROWS;
  constexpr int MW = BM / WROWS;
  constexpr int NW = CO / WCOLS;
  constexpr int MFR = MW / 16;
  constexpr int NFR = NW / 16;
  const int wave = tid >> 6, lane = tid & 63;
  const int wm = wave / WCOLS, wn = wave % WCOLS;
  const int mb = wm * MW, nb = wn * NW;
  const int lr = lane & 15, kq = lane >> 4;

  f32x4 acc[MFR][NFR] = {};
#pragma unroll
  for (int ks = 0; ks < 4; ks++) {
    const int kof = (ks * 32 + kq * 8) * 2;
    s16x8 af[MFR], bfr[NFR];
#pragma unroll
    for (int mf = 0; mf < MFR; mf++) {
      int r = mb + mf * 16 + lr;
      af[mf] = *(const s16x8*)(As + ((r * 256 + kof) ^ ((r & 7) << 4)));
    }
#pragma unroll
    for (int nf = 0; nf < NFR; nf++) {
      int r = nb + nf * 16 + lr;
      bfr[nf] = *(const s16x8*)(Bs + ((r * 256 + kof) ^ ((r & 7) << 4)));
    }
#pragma unroll
    for (int mf = 0; mf < MFR; mf++)
#pragma unroll
      for (int nf = 0; nf < NFR; nf++)
        acc[mf][nf] = __builtin_amdgcn_mfma_f32_16x16x32_bf16(af[mf], bfr[nf], acc[mf][nf], 0, 0, 0);
  }

#pragma unroll
  for (int mf = 0; mf < MFR; mf++) {
#pragma unroll
    for (int nf = 0; nf < NFR; nf++) {
      const int col = nb + nf * 16 + lr;
      const float bcol = bias[col];
      float ew = 0.f;
      if constexpr (DEPTH) ew = extraW[col];
#pragma unroll
      for (int r = 0; r < 4; r++) {
        long row = row0 + mb + mf * 16 + kq * 4 + r;
        float val = acc[mf][nf][r] + bcol;
        if constexpr (DEPTH) val += ew * (A2[row] * (1.0f / 55.0f));
        if constexpr (DOGELU) val = gelu_f(val);
        if constexpr (SPLIT) {
          if (col < 96) outF[row * 96 + col] = val;
          else if (col < 144) outB[row * 48 + (col - 96)] = bf16rne(val);
        } else {
          if constexpr (WF) outF[row * CO + col] = val;
          if constexpr (WBF) outB[row * CO + col] = bf16rne(val);
        }
      }
    }
  }
}

// ============ final GEMM: y = acat[16384][256] @ Wcat[128][256]^T + cvec ============
__global__ __launch_bounds__(NT)
void final_gemm(const u16* __restrict__ A, const u16* __restrict__ Wc,
                const float* __restrict__ cvec, float* __restrict__ outY)
{
  __shared__ char As[64 * 512];
  const int tid = threadIdx.x;
  const long row0 = (long)blockIdx.x * 64;
  for (int i = tid; i < 64 * 32; i += NT) {
    int r = i >> 5, ck = i & 31;
    u32x4 v = ((const u32x4*)(A + (row0 + r) * 256))[ck];
    *(u32x4*)(As + ((r * 512 + ck * 16) ^ ((r & 7) << 4))) = v;
  }
  __syncthreads();
  const int wave = tid >> 6, lane = tid & 63;
  const int mb = wave * 16;
  const int lr = lane & 15, kq = lane >> 4;
  f32x4 acc[8] = {};
#pragma unroll
  for (int ks = 0; ks < 8; ks++) {
    const int kof = (ks * 32 + kq * 8) * 2;
    const int r = mb + lr;
    s16x8 af = *(const s16x8*)(As + ((r * 512 + kof) ^ ((r & 7) << 4)));
#pragma unroll
    for (int nf = 0; nf < 8; nf++) {
      s16x8 bfr = *(const s16x8*)(Wc + (nf * 16 + lr) * 256 + ks * 32 + kq * 8);
      acc[nf] = __builtin_amdgcn_mfma_f32_16x16x32_bf16(af, bfr, acc[nf], 0, 0, 0);
    }
  }
#pragma unroll
  for (int nf = 0; nf < 8; nf++) {
    int col = nf * 16 + lr;
    float bcol = cvec[col];
#pragma unroll
    for (int r = 0; r < 4; r++) {
      long row = row0 + mb + kq * 4 + r;
      outY[row * 128 + col] = acc[nf][r] + bcol;
    }
  }
}

// ---------------- combine: s̄,q̄ per pixel -> acat [pix][256] bf16 ----------------
__global__ __launch_bounds__(NT)
void combine_kernel(const u16* __restrict__ smp, const u16* __restrict__ query,
                    const float* __restrict__ wgt, u16* __restrict__ acat)
{
  const long idx = (long)blockIdx.x * NT + threadIdx.x;   // 131072 = 16384 pix x 8 seg
  const long pix = idx >> 3;
  const int c0 = (idx & 7) * 16;
  float w[5];
#pragma unroll
  for (int k = 0; k < 5; k++) w[k] = wgt[pix * 5 + k];
  float as[16] = {}, aq[16] = {};
#pragma unroll
  for (int k = 0; k < 5; k++) {
    const u32x4* sp = (const u32x4*)(smp + (pix * 5 + k) * 128 + c0);
    const u32x4* qp = (const u32x4*)(query + (pix * 5 + k) * 128 + c0);
    u32x4 s0 = sp[0], s1 = sp[1], q0 = qp[0], q1 = qp[1];
#pragma unroll
    for (int e = 0; e < 4; e++) {
      as[2 * e]     += w[k] * bflo(s0[e]);  as[2 * e + 1] += w[k] * bfhi(s0[e]);
      as[8 + 2 * e] += w[k] * bflo(s1[e]);  as[9 + 2 * e] += w[k] * bfhi(s1[e]);
      aq[2 * e]     += w[k] * bflo(q0[e]);  aq[2 * e + 1] += w[k] * bfhi(q0[e]);
      aq[8 + 2 * e] += w[k] * bflo(q1[e]);  aq[9 + 2 * e] += w[k] * bfhi(q1[e]);
    }
  }
  u32x4 o0, o1, o2, o3;
#pragma unroll
  for (int e = 0; e < 4; e++) {
    o0[e] = (u32)bf16rne(as[2 * e]) | ((u32)bf16rne(as[2 * e + 1]) << 16);
    o1[e] = (u32)bf16rne(as[8 + 2 * e]) | ((u32)bf16rne(as[9 + 2 * e]) << 16);
    o2[e] = (u32)bf16rne(aq[2 * e]) | ((u32)bf16rne(aq[2 * e + 1]) << 16);
    o3[e] = (u32)bf16rne(aq[8 + 2 * e]) | ((u32)bf16rne(aq[9 + 2 * e]) << 16);
  }
  u32x4* dst = (u32x4*)(acat + pix * 256 + c0);
  dst[0] = o0; dst[1] = o1;
  u32x4* dst2 = (u32x4*)(acat + pix * 256 + 128 + c0);
  dst2[0] = o2; dst2[1] = o3;
}

// ---------------- small prep kernels ----------------
__global__ void wcomb_kernel(const float* __restrict__ vp_w, const float* __restrict__ wv,
                             const float* __restrict__ vp_b, const float* __restrict__ bv,
                             u16* __restrict__ wc, float* __restrict__ bc)
{
  int o = blockIdx.x;
  int c = threadIdx.x;
  float s = 0.f;
  for (int m = 0; m < 128; m++) s += vp_w[o * 128 + m] * wv[m * 128 + c];
  wc[o * 128 + c] = bf16rne(s);
  if (c == 0) {
    float b = vp_b[o];
    for (int m = 0; m < 128; m++) b += vp_w[o * 128 + m] * bv[m];
    bc[o] = b;
  }
}

// Wcat[o][c] = (wo @ op_w)[o][c] (c<128) | wo[o][c-128]; cvec = wo@op_b + bo
__global__ void wopcomb_kernel(const float* __restrict__ wo, const float* __restrict__ op_w,
                               const float* __restrict__ op_b, const float* __restrict__ bo,
                               u16* __restrict__ Wcat, float* __restrict__ cvec)
{
  int o = blockIdx.x;
  int c = threadIdx.x;
  float s = 0.f;
  for (int m = 0; m < 128; m++) s += wo[o * 128 + m] * op_w[m * 128 + c];
  Wcat[o * 256 + c] = bf16rne(s);
  Wcat[o * 256 + 128 + c] = bf16rne(wo[o * 128 + c]);
  if (c == 0) {
    float b = bo[o];
    for (int m = 0; m < 128; m++) b += wo[o * 128 + m] * op_b[m];
    cvec[o] = b;
  }
}

__global__ void cvtw_kernel(const float* __restrict__ qd_w1, const float* __restrict__ qd_w2,
                            const float* __restrict__ off_w, const float* __restrict__ aw_w,
                            const float* __restrict__ off_b, const float* __restrict__ aw_b,
                            u16* Wq1, u16* Wq2, u16* Wmg, float* mgbias, float* w1last)
{
  int i = blockIdx.x * NT + threadIdx.x;
  if (i < 16384) {
    int r = i >> 7, c = i & 127;
    Wq1[i] = bf16rne(qd_w1[r * 129 + c]);
    Wq2[i] = bf16rne(qd_w2[i]);
  }
  if (i < 20480) {
    int r = i >> 7, c = i & 127;
    float v = (r < 96) ? off_w[r * 128 + c] : ((r < 144) ? aw_w[(r - 96) * 128 + c] : 0.f);
    Wmg[i] = bf16rne(v);
  }
  if (i < 160) mgbias[i] = (i < 96) ? off_b[i] : ((i < 144) ? aw_b[i - 96] : 0.f);
  if (i < 128) w1last[i] = qd_w1[i * 129 + 128];
}

__global__ void packw_kernel(const float* __restrict__ rh_w1, const float* __restrict__ rh_w3,
                             const float* __restrict__ wq, const float* __restrict__ rh_w2,
                             u32* Wh1, u32* Wlog, u32* Wq0, u32* Wcv)
{
  int i = blockIdx.x * NT + threadIdx.x;
  if (i < 128 * 96) {
    int r = i / 96, c = i % 96;
    Wh1[i] = packsplit(c < 67 ? rh_w1[r * 67 + c] : 0.f);
  }
  if (i < 112 * 64) {
    int r = i / 64, c = i % 64;
    Wlog[i] = packsplit(r < 110 ? rh_w3[r * 64 + c] : 0.f);
  }
  if (i < 128 * 64) Wq0[i] = packsplit(wq[i]);
  if (i < 9 * 64 * 128) {
    int t = i / (64 * 128), o = (i / 128) % 64, c = i % 128;
    Wcv[i] = packsplit(rh_w2[(o * 128 + c) * 9 + t]);
  }
}

__global__ void uvec_kernel(float* __restrict__ uvec)
{
  int pix = blockIdx.x * NT + threadIdx.x;
  if (pix >= 16384) return;
  int hr = pix >> 9;
  int w = pix & 511;
  float el = c_elev[31 - hr] * 0.017453292519943295f;
  float az = -3.14159265358979323846f + ((float)w + 0.5f) * (6.283185307179586477f / 512.0f);
  float ce = cosf(el);
  uvec[pix * 3 + 0] = cosf(az) * ce;
  uvec[pix * 3 + 1] = sinf(az) * ce;
  uvec[pix * 3 + 2] = sinf(el);
}

// ---------------- GroupNorm ----------------
template<int C, int S>
__global__ __launch_bounds__(NT)
void gn_stats_kernel(const float* __restrict__ X, int Npix, float* __restrict__ gs)
{
  constexpr int PPB = NT / C;
  int tid = threadIdx.x;
  int c = tid % C;
  int psub = tid / C;
  float sum = 0.f, ss = 0.f;
  for (long pix = (long)blockIdx.x * PPB + psub; pix < Npix; pix += (long)gridDim.x * PPB) {
    float v = X[pix * C + c];
    sum += v; ss += v * v;
  }
  __shared__ float ls[8][2];
  if (tid < 16) ls[tid / 2][tid % 2] = 0.f;
  __syncthreads();
  int g = c / S;
  atomicAdd(&ls[g][0], sum);
  atomicAdd(&ls[g][1], ss);
  __syncthreads();
  if (tid < 16) atomicAdd(&gs[tid], ls[tid / 2][tid % 2]);
}

template<int C, int S>
__global__ void gn_apply_kernel(float* __restrict__ X, long total, int Npix,
                                const float* __restrict__ gs,
                                const float* __restrict__ gamma, const float* __restrict__ beta)
{
  float cnt = (float)Npix * (float)S;
  for (long i = (long)blockIdx.x * NT + threadIdx.x; i < total; i += (long)gridDim.x * NT) {
    int c = (int)(i % C);
    int g = c / S;
    float mu = gs[g * 2] / cnt;
    float var = gs[g * 2 + 1] / cnt - mu * mu;
    float v = (X[i] - mu) * rsqrtf(var + 1e-5f);
    v = v * gamma[c] + beta[c];
    X[i] = gelu_f(v);
  }
}

// ---------------- logits transpose ----------------
__global__ __launch_bounds__(NT)
void tlogits_kernel(const float* __restrict__ logits, float* __restrict__ out1)
{
  __shared__ float ls[128][111];
  int p0 = blockIdx.x * 128;
  for (int i = threadIdx.x; i < 128 * 110; i += NT) {
    int p = i / 110, c = i % 110;
    ls[p][c] = logits[(long)(p0 + p) * 110 + c];
  }
  __syncthreads();
  for (int i = threadIdx.x; i < 110 * 128; i += NT) {
    int c = i / 128, p = i % 128;
    out1[(long)c * 16384 + p0 + p] = ls[p][c];
  }
}

// ---------------- softmax + top-5 per pixel ----------------
__global__ __launch_bounds__(NT)
void topk_kernel(const float* __restrict__ logits, float* __restrict__ depths,
                 float* __restrict__ wgt)
{
  int lane = threadIdx.x & 63;
  int pix = (blockIdx.x * NT + threadIdx.x) >> 6;
  const float* lr = logits + (long)pix * 110;
  float v0 = (lane < 110) ? lr[lane] : -1e30f;
  float v1 = (lane + 64 < 110) ? lr[lane + 64] : -1e30f;
  float m = fmaxf(v0, v1);
#pragma unroll
  for (int s = 32; s; s >>= 1) m = fmaxf(m, __shfl_xor(m, s));
  float ex = ((lane < 110) ? expf(v0 - m) : 0.f) + ((lane + 64 < 110) ? expf(v1 - m) : 0.f);
  float den = ex;
#pragma unroll
  for (int s = 32; s; s >>= 1) den += __shfl_xor(den, s);
  float pr[5]; int pi[5];
#pragma unroll
  for (int j = 0; j < 5; j++) {
    float bv; int bi;
    if (v0 >= v1) { bv = v0; bi = lane; } else { bv = v1; bi = lane + 64; }
    for (int s = 1; s < 64; s <<= 1) {
      float ov = __shfl_xor(bv, s);
      int oi = __shfl_xor(bi, s);
      if (ov > bv || (ov == bv && oi < bi)) { bv = ov; bi = oi; }
    }
    pr[j] = expf(bv - m) / den;
    pi[j] = bi;
    if (bi == lane) v0 = -1e30f;
    if (bi == lane + 64) v1 = -1e30f;
  }
  if (lane == 0) {
    float tot = pr[0] + pr[1] + pr[2] + pr[3] + pr[4] + 1e-8f;
#pragma unroll
    for (int j = 0; j < 5; j++) {
      depths[pix * 5 + j] = fminf(0.5f * ((float)pi[j] + 0.5f), 54.75f);
      wgt[pix * 5 + j] = pr[j] / tot;
    }
  }
}

// ---------------- reference points ----------------
__global__ void refq_kernel(const float* __restrict__ depths, const float* __restrict__ uvec,
                            const float* __restrict__ L44, float* __restrict__ refq)
{
  long q = (long)blockIdx.x * NT + threadIdx.x;
  if (q >= 81920) return;
  long pix = q / 5;
  float d = depths[q];
  float px = d * uvec[pix * 3 + 0];
  float py = d * uvec[pix * 3 + 1];
  float pz = d * uvec[pix * 3 + 2];
  float pex = px * L44[0] + py * L44[4] + pz * L44[8] + L44[12];
  float pey = px * L44[1] + py * L44[5] + pz * L44[9] + L44[13];
  float rx = (pex + 55.0f) / 110.0f;
  float ry = (pey + 55.0f) / 110.0f;
  refq[q * 2 + 0] = fminf(fmaxf(rx, 0.f), 1.f);
  refq[q * 2 + 1] = fminf(fmaxf(ry, 0.f), 1.f);
}

// ---------------- deformable sampling: k-major, 1 thread per (q,h), 16 ch ----------------
__global__ __launch_bounds__(NT)
void msda_kernel(const u16* __restrict__ V, const float* __restrict__ refq,
                 const float* __restrict__ offb, const u16* __restrict__ awb,
                 u16* __restrict__ S)
{
  const int tid = threadIdx.x;
  const int kk = blockIdx.x >> 9;            // depth slot 0..4 (512 pixel-groups each)
  const int pg = blockIdx.x & 511;
  const long pix = (long)pg * 32 + (tid >> 3);
  const int h = tid & 7;
  const long q = pix * 5 + kk;
  const int c0 = h * 16;
  const float rx = refq[q * 2 + 0], ry = refq[q * 2 + 1];

  // attention softmax (once per (q,h))
  const u32* ap32 = (const u32*)(awb + q * 48 + h * 6);
  u32 aw0 = ap32[0], aw1 = ap32[1], aw2 = ap32[2];
  float a[6] = { bflo(aw0), bfhi(aw0), bflo(aw1), bfhi(aw1), bflo(aw2), bfhi(aw2) };
  float mx = fmaxf(fmaxf(fmaxf(a[0], a[1]), fmaxf(a[2], a[3])), fmaxf(a[4], a[5]));
  float se = 0.f;
#pragma unroll
  for (int p = 0; p < 6; p++) { a[p] = __expf(a[p] - mx); se += a[p]; }
  const float inv = 1.0f / se;

  // offsets (3 x f32x4)
  const f32x4* opv = (const f32x4*)(offb + q * 96 + h * 12);
  f32x4 of0 = opv[0], of1 = opv[1], of2 = opv[2];
  const float ox[6] = { of0[0], of0[2], of1[0], of1[2], of2[0], of2[2] };
  const float oy[6] = { of0[1], of0[3], of1[1], of1[3], of2[1], of2[3] };

  float acc[16];
#pragma unroll
  for (int j = 0; j < 16; j++) acc[j] = 0.f;

#pragma unroll
  for (int p = 0; p < 6; p++) {
    float x = (rx + ox[p] * (1.0f / 256.0f)) * 256.0f - 0.5f;
    float y = (ry + oy[p] * (1.0f / 256.0f)) * 256.0f - 0.5f;
    float x0f = floorf(x), y0f = floorf(y);
    float wx = x - x0f, wy = y - y0f;
    int ix = (int)x0f, iy = (int)y0f;
    float awp = a[p] * inv;
    // separable validity-folded weights
    float wx0 = ((unsigned)ix < 256u) ? (1.f - wx) : 0.f;
    float wx1 = ((unsigned)(ix + 1) < 256u) ? wx : 0.f;
    float wy0 = ((unsigned)iy < 256u) ? (awp * (1.f - wy)) : 0.f;
    float wy1 = ((unsigned)(iy + 1) < 256u) ? (awp * wy) : 0.f;
    int xc0 = min(max(ix, 0), 255), xc1 = min(max(ix + 1, 0), 255);
    int yc0 = min(max(iy, 0), 255), yc1 = min(max(iy + 1, 0), 255);
#pragma unroll
    for (int cy = 0; cy < 2; cy++) {
      int yc = cy ? yc1 : yc0;
      float wyv = cy ? wy1 : wy0;
#pragma unroll
      for (int cx = 0; cx < 2; cx++) {
        int xc = cx ? xc1 : xc0;
        float m = (cx ? wx1 : wx0) * wyv;
        const u32x4* vp = (const u32x4*)(V + (yc * 256 + xc) * 128 + c0);
        u32x4 v0 = vp[0], v1 = vp[1];
#pragma unroll
        for (int e = 0; e < 4; e++) {
          acc[2 * e]     += m * bflo(v0[e]);  acc[2 * e + 1] += m * bfhi(v0[e]);
          acc[8 + 2 * e] += m * bflo(v1[e]);  acc[9 + 2 * e] += m * bfhi(v1[e]);
        }
      }
    }
  }
  u32x4 o0, o1;
#pragma unroll
  for (int e = 0; e < 4; e++) {
    o0[e] = (u32)bf16rne(acc[2 * e]) | ((u32)bf16rne(acc[2 * e + 1]) << 16);
    o1[e] = (u32)bf16rne(acc[8 + 2 * e]) | ((u32)bf16rne(acc[9 + 2 * e]) << 16);
  }
  u32x4* dst = (u32x4*)(S + q * 128 + c0);
  dst[0] = o0; dst[1] = o1;
}

} // namespace

extern "C" void kernel_launch(void* const* d_in, const int* in_sizes, int n_in,
                              void* d_out, int out_size, void* d_ws, size_t ws_size,
                              hipStream_t stream)
{
  (void)in_sizes; (void)n_in; (void)out_size; (void)ws_size;
  const float* x_rv   = (const float*)d_in[0];
  const float* bev    = (const float*)d_in[1];
  const float* L44    = (const float*)d_in[2];
  const float* wq     = (const float*)d_in[3];
  const float* bq     = (const float*)d_in[4];
  const float* wv     = (const float*)d_in[5];
  const float* bv     = (const float*)d_in[6];
  const float* woW    = (const float*)d_in[7];
  const float* boB    = (const float*)d_in[8];
  const float* qd_w1  = (const float*)d_in[9];
  const float* qd_b1  = (const float*)d_in[10];
  const float* qd_w2  = (const float*)d_in[11];
  const float* qd_b2  = (const float*)d_in[12];
  const float* rh_w1  = (const float*)d_in[13];
  const float* rh_b1  = (const float*)d_in[14];
  const float* rh_g1  = (const float*)d_in[15];
  const float* rh_be1 = (const float*)d_in[16];
  const float* rh_w2  = (const float*)d_in[17];
  const float* rh_g2  = (const float*)d_in[18];
  const float* rh_be2 = (const float*)d_in[19];
  const float* rh_w3  = (const float*)d_in[20];
  const float* rh_b3  = (const float*)d_in[21];
  const float* off_w  = (const float*)d_in[22];
  const float* off_b  = (const float*)d_in[23];
  const float* aw_w   = (const float*)d_in[24];
  const float* aw_b   = (const float*)d_in[25];
  const float* vp_w   = (const float*)d_in[26];
  const float* vp_b   = (const float*)d_in[27];
  const float* op_w   = (const float*)d_in[28];
  const float* op_b   = (const float*)d_in[29];

  float* outY = (float*)d_out;
  float* outL = (float*)d_out + 2097152;

  char* wsb = (char*)d_ws;
  size_t off = 0;
  auto alloc = [&](size_t bytes) -> char* {
    char* p = wsb + off;
    off += (bytes + 255) & ~(size_t)255;
    return p;
  };

  u16*   wcomb  = (u16*)alloc(32768);
  float* bcomb  = (float*)alloc(512);
  float* uvec   = (float*)alloc(196608);
  float* stats  = (float*)alloc(128);
  float* depths = (float*)alloc(327680);
  float* wgtb   = (float*)alloc(327680);
  float* refqb  = (float*)alloc(655360);
  float* w1last = (float*)alloc(512);
  u16*   Wq1    = (u16*)alloc(32768);
  u16*   Wq2    = (u16*)alloc(32768);
  u16*   Wmg    = (u16*)alloc(40960);
  float* mgbias = (float*)alloc(640);
  u16*   Wcat   = (u16*)alloc(65536);
  float* cvec   = (float*)alloc(512);
  u32*   Wh1    = (u32*)alloc(49152);
  u32*   Wlog   = (u32*)alloc(28672);
  u32*   Wq0    = (u32*)alloc(32768);
  u32*   Wcv    = (u32*)alloc(294912);
  char*  S1     = alloc(20971520);   // h1|logits|h2 -> smp
  char*  S2     = alloc(4194304);    // Q0 bf16
  char*  S3     = alloc(16777216);   // v bf16
  char*  S4     = alloc(20971520);   // q1 bf16 -> acat bf16
  char*  S5     = alloc(20971520);   // query bf16
  float* offbuf = (float*)alloc(31457280);
  u16*   awbf   = (u16*)alloc(7864320);

  float* h1buf  = (float*)S1;                   // [16384][128]
  float* logits = (float*)(S1 + 8388608);       // [16384][110]
  float* h2buf  = (float*)(S1 + 15597568);      // [16384][64]
  u16*   smp    = (u16*)S1;                     // [81920][128] (depth head dead)
  u16*   Q0bf   = (u16*)S2;
  u16*   vbuf   = (u16*)S3;
  u16*   q1bf   = (u16*)S4;
  u16*   acat   = (u16*)S4;                     // [16384][256] (q1 dead)
  u16*   querybf= (u16*)S5;

  float* stats1 = stats;
  float* stats2 = stats + 16;

  hipMemsetAsync((void*)stats, 0, 128, stream);

  // weight prep
  wcomb_kernel<<<128, 128, 0, stream>>>(vp_w, wv, vp_b, bv, wcomb, bcomb);
  wopcomb_kernel<<<128, 128, 0, stream>>>(woW, op_w, op_b, boB, Wcat, cvec);
  uvec_kernel<<<64, NT, 0, stream>>>(uvec);
  cvtw_kernel<<<80, NT, 0, stream>>>(qd_w1, qd_w2, off_w, aw_w, off_b, aw_b,
                                     Wq1, Wq2, Wmg, mgbias, w1last);
  packw_kernel<<<288, NT, 0, stream>>>(rh_w1, rh_w3, wq, rh_w2, Wh1, Wlog, Wq0, Wcv);

  // Q0 = x_rv @ wq^T + bq  (single-f16 MFMA, bf16 out)
  slin<128, 128, 64, 64, 1, 0, false, true><<<256, NT, 0, stream>>>(
      x_rv, nullptr, Wq0, bq, nullptr, Q0bf);

  // depth head (split-f16 MFMA ~ f32 accuracy)
  slin<128, 128, 96, 67, 3, 1, false, false><<<256, NT, 0, stream>>>(
      x_rv, uvec, Wh1, rh_b1, h1buf, nullptr);
  gn_stats_kernel<128, 16><<<512, NT, 0, stream>>>(h1buf, 16384, stats1);
  gn_apply_kernel<128, 16><<<2048, NT, 0, stream>>>(h1buf, 16384L * 128, 16384, stats1, rh_g1, rh_be1);
  conv_mfma<<<512, NT, 0, stream>>>(h1buf, Wcv, h2buf);
  gn_stats_kernel<64, 8><<<512, NT, 0, stream>>>(h2buf, 16384, stats2);
  gn_apply_kernel<64, 8><<<1024, NT, 0, stream>>>(h2buf, 16384L * 64, 16384, stats2, rh_g2, rh_be2);
  slin<110, 112, 64, 64, 3, 0, false, false><<<256, NT, 0, stream>>>(
      h2buf, nullptr, Wlog, rh_b3, logits, nullptr);
  tlogits_kernel<<<128, NT, 0, stream>>>(logits, outL);
  topk_kernel<<<4096, NT, 0, stream>>>(logits, depths, wgtb);
  refq_kernel<<<320, NT, 0, stream>>>(depths, uvec, L44, refqb);

  // v = bev(NCHW) @ (vp_w . wv)^T + bias -> bf16 [65536][128]
  mfma_lin<128, 4, false, false, false, true, false><<<1024, NT, 0, stream>>>(
      bev, nullptr, wcomb, bcomb, nullptr, nullptr, vbuf, 65536);

  // query MLP
  mfma_lin<128, 1, true, true, false, true, false><<<1280, NT, 0, stream>>>(
      Q0bf, depths, Wq1, qd_b1, w1last, nullptr, q1bf, 0);
  mfma_lin<128, 0, false, false, false, true, false><<<1280, NT, 0, stream>>>(
      q1bf, nullptr, Wq2, qd_b2, nullptr, nullptr, querybf, 0);

  // merged offsets (f32) + attention logits (bf16), CO=160
  mfma_lin<160, 0, false, false, false, false, true><<<1280, NT, 0, stream>>>(
      querybf, nullptr, Wmg, mgbias, nullptr, offbuf, awbf, 0);

  // deformable sampling (k-major, 16 ch/thread)
  msda_kernel<<<2560, NT, 0, stream>>>(vbuf, refqb, offbuf, awbf, smp);

  // per-pixel combine: acat = [ Σk wgt·smp | Σk wgt·query ]
  combine_kernel<<<512, NT, 0, stream>>>(smp, querybf, wgtb, acat);

  // final: y = acat @ [wo·op | wo]^T + (wo·op_b + bo)
  final_gemm<<<256, NT, 0, stream>>>(acat, Wcat, cvec, outY);
}

// Round 7
// 406.944 us; speedup vs baseline: 1.1115x; 1.1115x over previous
//
#include <hip/hip_runtime.h>
#include <math.h>

#define NT 256

typedef unsigned short u16;
typedef unsigned int u32;
typedef _Float16 f16;
typedef __attribute__((ext_vector_type(2))) unsigned int u32x2;
typedef __attribute__((ext_vector_type(4))) unsigned int u32x4;
typedef __attribute__((ext_vector_type(4))) float f32x4;
typedef __attribute__((ext_vector_type(8))) short s16x8;
typedef __attribute__((ext_vector_type(8))) _Float16 f16x8;

namespace {

__device__ const float c_elev[32] = {
  -30.67f,-29.33f,-28.0f,-26.66f,-25.33f,-24.0f,-22.67f,-21.33f,
  -20.0f,-18.67f,-17.33f,-16.0f,-14.67f,-13.33f,-12.0f,-10.67f,
  -9.33f,-8.0f,-6.66f,-5.33f,-4.0f,-2.67f,-1.33f,0.0f,1.33f,
  2.67f,4.0f,5.33f,6.67f,8.0f,9.33f,10.67f };

__device__ __forceinline__ float gelu_f(float x) {
  return 0.5f * x * (1.0f + erff(x * 0.70710678118654752440f));
}
__device__ __forceinline__ u16 bf16rne(float f) {
  u32 u = __builtin_bit_cast(u32, f);
  u32 r = u + 0x7FFFu + ((u >> 16) & 1u);
  return (u16)(r >> 16);
}
__device__ __forceinline__ float bf2f(u16 h) {
  u32 u = ((u32)h) << 16;
  return __builtin_bit_cast(float, u);
}
__device__ __forceinline__ float bflo(u32 v) {
  return __builtin_bit_cast(float, v << 16);
}
__device__ __forceinline__ float bfhi(u32 v) {
  return __builtin_bit_cast(float, v & 0xFFFF0000u);
}
__device__ __forceinline__ u32 packsplit(float x) {
  f16 h = (f16)x;
  f16 l = (f16)(x - (float)h);
  return (u32)__builtin_bit_cast(u16, h) | ((u32)__builtin_bit_cast(u16, l) << 16);
}
__device__ __forceinline__ void unpack16(u32x4 a, u32x4 b, f16x8& hi, f16x8& lo) {
  u32x4 h, l;
  h[0] = (a[0] & 0xFFFFu) | (a[1] << 16);  l[0] = (a[0] >> 16) | (a[1] & 0xFFFF0000u);
  h[1] = (a[2] & 0xFFFFu) | (a[3] << 16);  l[1] = (a[2] >> 16) | (a[3] & 0xFFFF0000u);
  h[2] = (b[0] & 0xFFFFu) | (b[1] << 16);  l[2] = (b[0] >> 16) | (b[1] & 0xFFFF0000u);
  h[3] = (b[2] & 0xFFFFu) | (b[3] << 16);  l[3] = (b[2] >> 16) | (b[3] & 0xFFFF0000u);
  hi = __builtin_bit_cast(f16x8, h);
  lo = __builtin_bit_cast(f16x8, l);
}

// ============ split-f16 MFMA linear, depth path ============
// AMODE: 0 = f32 row-major A [N][CI]; 1 = cat(x_rv[pix][64], uvec[pix][3])
// GN: apply GroupNorm(C=64,S=8 via gs/gamma/beta)+gelu at staging (logits GEMM)
template<int COREAL, int CO, int KPAD, int CI, int PROD, int AMODE, bool DOGELU, bool OBF, bool GN = false>
__global__ __launch_bounds__(NT)
void slin(const float* __restrict__ Af, const float* __restrict__ A2,
          const u32* __restrict__ Wp, const float* __restrict__ bias,
          const float* __restrict__ gs, const float* __restrict__ gamma,
          const float* __restrict__ beta,
          float* __restrict__ outF, u16* __restrict__ outB)
{
  constexpr int BM = 64;
  constexpr int NFR = CO / 16;
  constexpr int KS = KPAD / 32;
  __shared__ u32 lds[BM * KPAD];
  const int tid = threadIdx.x;
  const long row0 = (long)blockIdx.x * BM;

  for (int i = tid; i < BM * (KPAD / 4); i += NT) {
    int r = i / (KPAD / 4), c = (i % (KPAD / 4)) * 4;
    long pix = row0 + r;
    u32x4 o;
    if constexpr (AMODE == 0) {
      if (c + 3 < CI) {
        f32x4 v = *(const f32x4*)(Af + pix * CI + c);
#pragma unroll
        for (int e = 0; e < 4; e++) {
          float x = v[e];
          if constexpr (GN) {
            int cc = c + e, g = cc >> 3;
            float mu = gs[2 * g] * (1.0f / 131072.0f);
            float var = gs[2 * g + 1] * (1.0f / 131072.0f) - mu * mu;
            x = (x - mu) * rsqrtf(var + 1e-5f) * gamma[cc] + beta[cc];
            x = gelu_f(x);
          }
          o[e] = packsplit(x);
        }
      } else {
#pragma unroll
        for (int e = 0; e < 4; e++) {
          int cc = c + e;
          float x = (cc < CI) ? Af[pix * CI + cc] : 0.f;
          if constexpr (GN) {
            if (cc < CI) {
              int g = cc >> 3;
              float mu = gs[2 * g] * (1.0f / 131072.0f);
              float var = gs[2 * g + 1] * (1.0f / 131072.0f) - mu * mu;
              x = (x - mu) * rsqrtf(var + 1e-5f) * gamma[cc] + beta[cc];
              x = gelu_f(x);
            }
          }
          o[e] = packsplit(x);
        }
      }
    } else {
      if (c + 3 < 64) {
        f32x4 v = *(const f32x4*)(Af + pix * 64 + c);
#pragma unroll
        for (int e = 0; e < 4; e++) o[e] = packsplit(v[e]);
      } else {
#pragma unroll
        for (int e = 0; e < 4; e++) {
          int cc = c + e;
          float x = (cc < 64) ? Af[pix * 64 + cc] : ((cc < 67) ? A2[pix * 3 + cc - 64] : 0.f);
          o[e] = packsplit(x);
        }
      }
    }
    *(u32x4*)((char*)lds + (((r * KPAD + c) * 4) ^ ((r & 7) << 4))) = o;
  }
  __syncthreads();

  const int wave = tid >> 6, lane = tid & 63;
  const int mb = wave * 16;
  const int lr = lane & 15, kq = lane >> 4;

  f32x4 acc[NFR] = {};
#pragma unroll
  for (int ks = 0; ks < KS; ks++) {
    const int arow = mb + lr;
    const u32 sw = (arow & 7) << 4;
    const int base = arow * KPAD * 4 + ks * 128 + kq * 32;
    u32x4 a0 = *(const u32x4*)((char*)lds + (base ^ sw));
    u32x4 a1 = *(const u32x4*)((char*)lds + ((base + 16) ^ sw));
    f16x8 ah, al;
    unpack16(a0, a1, ah, al);
#pragma unroll
    for (int nf = 0; nf < NFR; nf++) {
      const u32* wp = Wp + (nf * 16 + lr) * KPAD + ks * 32 + kq * 8;
      u32x4 w0 = *(const u32x4*)wp;
      u32x4 w1 = *(const u32x4*)(wp + 4);
      f16x8 wh, wl;
      unpack16(w0, w1, wh, wl);
      acc[nf] = __builtin_amdgcn_mfma_f32_16x16x32_f16(ah, wh, acc[nf], 0, 0, 0);
      if constexpr (PROD == 3) {
        acc[nf] = __builtin_amdgcn_mfma_f32_16x16x32_f16(ah, wl, acc[nf], 0, 0, 0);
        acc[nf] = __builtin_amdgcn_mfma_f32_16x16x32_f16(al, wh, acc[nf], 0, 0, 0);
      }
    }
  }

#pragma unroll
  for (int nf = 0; nf < NFR; nf++) {
    int col = nf * 16 + lr;
    if (col >= COREAL) continue;
    float bcol = bias[col];
#pragma unroll
    for (int r = 0; r < 4; r++) {
      long row = row0 + mb + kq * 4 + r;
      float val = acc[nf][r] + bcol;
      if constexpr (DOGELU) val = gelu_f(val);
      if constexpr (OBF) outB[row * COREAL + col] = bf16rne(val);
      else               outF[row * COREAL + col] = val;
    }
  }
}

// ============ 3x3 circular conv 128->64, GN1+gelu folded into staging ============
__global__ __launch_bounds__(NT)
void conv_mfma(const float* __restrict__ X, const u32* __restrict__ Wc,
               const float* __restrict__ gs, const float* __restrict__ gamma,
               const float* __restrict__ beta, float* __restrict__ Y)
{
  __shared__ u32 lds[4 * 18 * 128];
  const int tid = threadIdx.x;
  const int bRow = (blockIdx.x >> 5) * 2;
  const int bCol = (blockIdx.x & 31) * 16;

  for (int i = tid; i < 4 * 18 * 32; i += NT) {
    int c4 = (i & 31) * 4;
    int col = (i >> 5) % 18;
    int row = i / (18 * 32);
    int gy = (bRow + row - 1 + 32) & 31;
    int gx = (bCol + col - 1 + 512) & 511;
    f32x4 v = *(const f32x4*)(X + ((long)gy * 512 + gx) * 128 + c4);
    u32x4 o;
#pragma unroll
    for (int e = 0; e < 4; e++) {
      int cc = c4 + e, g = cc >> 4;
      float mu = gs[2 * g] * (1.0f / 262144.0f);
      float var = gs[2 * g + 1] * (1.0f / 262144.0f) - mu * mu;
      float x = (v[e] - mu) * rsqrtf(var + 1e-5f) * gamma[cc] + beta[cc];
      o[e] = packsplit(gelu_f(x));
    }
    *(u32x4*)((char*)lds + ((((row * 18 + col) * 128 + c4) * 4) ^ ((col & 7) << 4))) = o;
  }
  __syncthreads();

  const int wave = tid >> 6, lane = tid & 63;
  const int wm = wave >> 1;
  const int nb = (wave & 1) * 32;
  const int lr = lane & 15, kq = lane >> 4;

  f32x4 acc[2] = {};
  for (int t = 0; t < 9; t++) {
    const int ky = t / 3, kx = t % 3;
    const int wrow = wm + ky;
    const int wcol = lr + kx;
    const u32 sw = (wcol & 7) << 4;
    const int rowbase = (wrow * 18 + wcol) * 512;
#pragma unroll
    for (int ks = 0; ks < 4; ks++) {
      const int base = rowbase + ks * 128 + kq * 32;
      u32x4 a0 = *(const u32x4*)((char*)lds + (base ^ sw));
      u32x4 a1 = *(const u32x4*)((char*)lds + ((base + 16) ^ sw));
      f16x8 ah, al;
      unpack16(a0, a1, ah, al);
#pragma unroll
      for (int nf = 0; nf < 2; nf++) {
        const u32* wp = Wc + ((t * 64 + nb + nf * 16 + lr) * 128 + ks * 32 + kq * 8);
        u32x4 w0 = *(const u32x4*)wp;
        u32x4 w1 = *(const u32x4*)(wp + 4);
        f16x8 wh, wl;
        unpack16(w0, w1, wh, wl);
        acc[nf] = __builtin_amdgcn_mfma_f32_16x16x32_f16(ah, wh, acc[nf], 0, 0, 0);
        acc[nf] = __builtin_amdgcn_mfma_f32_16x16x32_f16(ah, wl, acc[nf], 0, 0, 0);
        acc[nf] = __builtin_amdgcn_mfma_f32_16x16x32_f16(al, wh, acc[nf], 0, 0, 0);
      }
    }
  }

  const int gy = bRow + wm;
#pragma unroll
  for (int nf = 0; nf < 2; nf++) {
    int co = nb + nf * 16 + lr;
#pragma unroll
    for (int r = 0; r < 4; r++) {
      int gx = bCol + kq * 4 + r;
      Y[((long)gy * 512 + gx) * 64 + co] = acc[nf][r];
    }
  }
}

// ================= bf16 MFMA linear (v-proj, mg160) =================
template<int CO, int AMODE, bool DEPTH, bool DOGELU, bool WF, bool WBF, bool SPLIT>
__global__ __launch_bounds__(NT)
void mfma_lin(const void* __restrict__ Ap, const float* __restrict__ A2,
              const u16* __restrict__ Wb, const float* __restrict__ bias,
              const float* __restrict__ extraW,
              float* __restrict__ outF, u16* __restrict__ outB, int ldA)
{
  constexpr int BM = 64;
  __shared__ u32x4 smem[(BM + CO) * 16];
  char* As = (char*)smem;
  char* Bs = (char*)smem + BM * 256;
  const int tid = threadIdx.x;
  const long row0 = (long)blockIdx.x * BM;

  for (int i = tid; i < CO * 16; i += NT) {
    int r = i >> 4, ck = i & 15;
    u32x4 v = ((const u32x4*)(Wb + r * 128))[ck];
    *(u32x4*)(Bs + ((r * 256 + ck * 16) ^ ((r & 7) << 4))) = v;
  }
  if constexpr (AMODE == 0 || AMODE == 1) {
    const u16* A = (const u16*)Ap;
    for (int i = tid; i < BM * 16; i += NT) {
      int r = i >> 4, ck = i & 15;
      long src = (AMODE == 1) ? ((row0 + r) / 5) : (row0 + r);
      u32x4 v = ((const u32x4*)(A + src * 128))[ck];
      *(u32x4*)(As + ((r * 256 + ck * 16) ^ ((r & 7) << 4))) = v;
    }
  } else if constexpr (AMODE == 4) {
    const float* A = (const float*)Ap;
    for (int i = tid; i < 128 * 16; i += NT) {
      int k = i >> 4, rg = i & 15;
      f32x4 v = *(const f32x4*)(A + (long)k * ldA + row0 + rg * 4);
#pragma unroll
      for (int e = 0; e < 4; e++) {
        int r = rg * 4 + e;
        *(u16*)(As + ((r * 256 + k * 2) ^ ((r & 7) << 4))) = bf16rne(v[e]);
      }
    }
  }
  __syncthreads();

  constexpr int WROWS = (CO >= 96) ? 2 : 4;
  constexpr int WCOLS = 4 / WROWS;
  constexpr int MW = BM / WROWS;
  constexpr int NW = CO / WCOLS;
  constexpr int MFR = MW / 16;
  constexpr int NFR = NW / 16;
  const int wave = tid >> 6, lane = tid & 63;
  const int wm = wave / WCOLS, wn = wave % WCOLS;
  const int mb = wm * MW, nb = wn * NW;
  const int lr = lane & 15, kq = lane >> 4;

  f32x4 acc[MFR][NFR] = {};
#pragma unroll
  for (int ks = 0; ks < 4; ks++) {
    const int kof = (ks * 32 + kq * 8) * 2;
    s16x8 af[MFR], bfr[NFR];
#pragma unroll
    for (int mf = 0; mf < MFR; mf++) {
      int r = mb + mf * 16 + lr;
      af[mf] = *(const s16x8*)(As + ((r * 256 + kof) ^ ((r & 7) << 4)));
    }
#pragma unroll
    for (int nf = 0; nf < NFR; nf++) {
      int r = nb + nf * 16 + lr;
      bfr[nf] = *(const s16x8*)(Bs + ((r * 256 + kof) ^ ((r & 7) << 4)));
    }
#pragma unroll
    for (int mf = 0; mf < MFR; mf++)
#pragma unroll
      for (int nf = 0; nf < NFR; nf++)
        acc[mf][nf] = __builtin_amdgcn_mfma_f32_16x16x32_bf16(af[mf], bfr[nf], acc[mf][nf], 0, 0, 0);
  }

#pragma unroll
  for (int mf = 0; mf < MFR; mf++) {
#pragma unroll
    for (int nf = 0; nf < NFR; nf++) {
      const int col = nb + nf * 16 + lr;
      const float bcol = bias[col];
      float ew = 0.f;
      if constexpr (DEPTH) ew = extraW[col];
#pragma unroll
      for (int r = 0; r < 4; r++) {
        long row = row0 + mb + mf * 16 + kq * 4 + r;
        float val = acc[mf][nf][r] + bcol;
        if constexpr (DEPTH) val += ew * (A2[row] * (1.0f / 55.0f));
        if constexpr (DOGELU) val = gelu_f(val);
        if constexpr (SPLIT) {
          if (col < 96) outF[row * 96 + col] = val;
          else if (col < 144) outB[row * 48 + (col - 96)] = bf16rne(val);
        } else {
          if constexpr (WF) outF[row * CO + col] = val;
          if constexpr (WBF) outB[row * CO + col] = bf16rne(val);
        }
      }
    }
  }
}

// ============ fused query MLP: query = (gelu(qin@W1^T+b1))@W2^T+b2 ============
__global__ __launch_bounds__(NT)
void qmlp_kernel(const u16* __restrict__ Q0, const float* __restrict__ depths,
                 const u16* __restrict__ W1, const float* __restrict__ b1,
                 const float* __restrict__ w1last,
                 const u16* __restrict__ W2, const float* __restrict__ b2,
                 u16* __restrict__ query)
{
  __shared__ char smem[49152];
  char* As = smem;            // 16KB: [64][128] bf16 swz
  char* Bs = smem + 16384;    // 32KB: [128][128] bf16 swz
  const int tid = threadIdx.x;
  const long row0 = (long)blockIdx.x * 64;

  for (int i = tid; i < 128 * 16; i += NT) {
    int r = i >> 4, ck = i & 15;
    u32x4 v = ((const u32x4*)(W1 + r * 128))[ck];
    *(u32x4*)(Bs + ((r * 256 + ck * 16) ^ ((r & 7) << 4))) = v;
  }
  for (int i = tid; i < 64 * 16; i += NT) {
    int r = i >> 4, ck = i & 15;
    long src = (row0 + r) / 5;
    u32x4 v = ((const u32x4*)(Q0 + src * 128))[ck];
    *(u32x4*)(As + ((r * 256 + ck * 16) ^ ((r & 7) << 4))) = v;
  }
  __syncthreads();

  const int wave = tid >> 6, lane = tid & 63;
  const int wm = wave >> 1, wn = wave & 1;
  const int mb = wm * 32, nb = wn * 64;
  const int lr = lane & 15, kq = lane >> 4;

  f32x4 acc[2][4] = {};
#pragma unroll
  for (int ks = 0; ks < 4; ks++) {
    const int kof = (ks * 32 + kq * 8) * 2;
    s16x8 af[2], bfr[4];
#pragma unroll
    for (int mf = 0; mf < 2; mf++) {
      int r = mb + mf * 16 + lr;
      af[mf] = *(const s16x8*)(As + ((r * 256 + kof) ^ ((r & 7) << 4)));
    }
#pragma unroll
    for (int nf = 0; nf < 4; nf++) {
      int r = nb + nf * 16 + lr;
      bfr[nf] = *(const s16x8*)(Bs + ((r * 256 + kof) ^ ((r & 7) << 4)));
    }
#pragma unroll
    for (int mf = 0; mf < 2; mf++)
#pragma unroll
      for (int nf = 0; nf < 4; nf++)
        acc[mf][nf] = __builtin_amdgcn_mfma_f32_16x16x32_bf16(af[mf], bfr[nf], acc[mf][nf], 0, 0, 0);
  }
  __syncthreads();   // all GEMM1 LDS reads drained

  // q1 -> LDS (As), W2 -> Bs
#pragma unroll
  for (int mf = 0; mf < 2; mf++) {
#pragma unroll
    for (int nf = 0; nf < 4; nf++) {
      int col = nb + nf * 16 + lr;
      float bcol = b1[col], ew = w1last[col];
#pragma unroll
      for (int r = 0; r < 4; r++) {
        int lrow = mb + mf * 16 + kq * 4 + r;
        float val = acc[mf][nf][r] + bcol + ew * (depths[row0 + lrow] * (1.0f / 55.0f));
        val = gelu_f(val);
        *(u16*)(As + ((lrow * 256 + col * 2) ^ ((lrow & 7) << 4))) = bf16rne(val);
      }
    }
  }
  for (int i = tid; i < 128 * 16; i += NT) {
    int r = i >> 4, ck = i & 15;
    u32x4 v = ((const u32x4*)(W2 + r * 128))[ck];
    *(u32x4*)(Bs + ((r * 256 + ck * 16) ^ ((r & 7) << 4))) = v;
  }
  __syncthreads();

  f32x4 acc2[2][4] = {};
#pragma unroll
  for (int ks = 0; ks < 4; ks++) {
    const int kof = (ks * 32 + kq * 8) * 2;
    s16x8 af[2], bfr[4];
#pragma unroll
    for (int mf = 0; mf < 2; mf++) {
      int r = mb + mf * 16 + lr;
      af[mf] = *(const s16x8*)(As + ((r * 256 + kof) ^ ((r & 7) << 4)));
    }
#pragma unroll
    for (int nf = 0; nf < 4; nf++) {
      int r = nb + nf * 16 + lr;
      bfr[nf] = *(const s16x8*)(Bs + ((r * 256 + kof) ^ ((r & 7) << 4)));
    }
#pragma unroll
    for (int mf = 0; mf < 2; mf++)
#pragma unroll
      for (int nf = 0; nf < 4; nf++)
        acc2[mf][nf] = __builtin_amdgcn_mfma_f32_16x16x32_bf16(af[mf], bfr[nf], acc2[mf][nf], 0, 0, 0);
  }
#pragma unroll
  for (int mf = 0; mf < 2; mf++) {
#pragma unroll
    for (int nf = 0; nf < 4; nf++) {
      int col = nb + nf * 16 + lr;
      float bcol = b2[col];
#pragma unroll
      for (int r = 0; r < 4; r++) {
        long row = row0 + mb + mf * 16 + kq * 4 + r;
        query[row * 128 + col] = bf16rne(acc2[mf][nf][r] + bcol);
      }
    }
  }
}

// ============ fused combine + output projection ============
// acat (LDS) = [ Σk wgt·smp | Σk wgt·query ]; y = acat @ Wcat^T + cvec
__global__ __launch_bounds__(NT)
void outproj_kernel(const u16* __restrict__ smp, const u16* __restrict__ query,
                    const float* __restrict__ wgt, const u16* __restrict__ Wcat,
                    const float* __restrict__ cvec, float* __restrict__ outY)
{
  __shared__ char As[64 * 512];   // 32KB [64][256] bf16 swz
  const int tid = threadIdx.x;
  const long pix0 = (long)blockIdx.x * 64;

#pragma unroll
  for (int t = 0; t < 8; t++) {
    int task = tid + t * 256;
    int r = task >> 5, ch = task & 31;
    long pix = pix0 + r;
    const u16* src = (ch < 16) ? smp : query;
    int cc = (ch & 15) * 8;
    float acc[8] = {};
#pragma unroll
    for (int k = 0; k < 5; k++) {
      float w = wgt[pix * 5 + k];
      u32x4 v = *(const u32x4*)(src + (pix * 5 + k) * 128 + cc);
#pragma unroll
      for (int e = 0; e < 4; e++) {
        acc[2 * e]     += w * bflo(v[e]);
        acc[2 * e + 1] += w * bfhi(v[e]);
      }
    }
    u32x4 o;
#pragma unroll
    for (int e = 0; e < 4; e++)
      o[e] = (u32)bf16rne(acc[2 * e]) | ((u32)bf16rne(acc[2 * e + 1]) << 16);
    *(u32x4*)(As + ((r * 512 + ch * 16) ^ ((r & 7) << 4))) = o;
  }
  __syncthreads();

  const int wave = tid >> 6, lane = tid & 63;
  const int wm = wave >> 1, wn = wave & 1;
  const int mb = wm * 32, nb = wn * 64;
  const int lr = lane & 15, kq = lane >> 4;

  f32x4 acc[2][4] = {};
#pragma unroll
  for (int ks = 0; ks < 8; ks++) {
    const int kof = (ks * 32 + kq * 8) * 2;
    s16x8 af[2], bfr[4];
#pragma unroll
    for (int mf = 0; mf < 2; mf++) {
      int r = mb + mf * 16 + lr;
      af[mf] = *(const s16x8*)(As + ((r * 512 + kof) ^ ((r & 7) << 4)));
    }
#pragma unroll
    for (int nf = 0; nf < 4; nf++)
      bfr[nf] = *(const s16x8*)(Wcat + (nb + nf * 16 + lr) * 256 + ks * 32 + kq * 8);
#pragma unroll
    for (int mf = 0; mf < 2; mf++)
#pragma unroll
      for (int nf = 0; nf < 4; nf++)
        acc[mf][nf] = __builtin_amdgcn_mfma_f32_16x16x32_bf16(af[mf], bfr[nf], acc[mf][nf], 0, 0, 0);
  }
#pragma unroll
  for (int mf = 0; mf < 2; mf++) {
#pragma unroll
    for (int nf = 0; nf < 4; nf++) {
      int col = nb + nf * 16 + lr;
      float bcol = cvec[col];
#pragma unroll
      for (int r = 0; r < 4; r++) {
        long row = pix0 + mb + mf * 16 + kq * 4 + r;
        outY[row * 128 + col] = acc[mf][nf][r] + bcol;
      }
    }
  }
}

// ---------------- prep: two 128x128 weight matmuls ----------------
__global__ void prepmm_kernel(const float* __restrict__ vp_w, const float* __restrict__ wv,
                              const float* __restrict__ vp_b, const float* __restrict__ bv,
                              const float* __restrict__ wo, const float* __restrict__ op_w,
                              const float* __restrict__ op_b, const float* __restrict__ bo,
                              u16* __restrict__ wc, float* __restrict__ bc,
                              u16* __restrict__ Wcat, float* __restrict__ cvec)
{
  int b = blockIdx.x, c = threadIdx.x;
  if (b < 128) {
    int o = b;
    float s = 0.f;
    for (int m = 0; m < 128; m++) s += vp_w[o * 128 + m] * wv[m * 128 + c];
    wc[o * 128 + c] = bf16rne(s);
    if (c == 0) {
      float bb = vp_b[o];
      for (int m = 0; m < 128; m++) bb += vp_w[o * 128 + m] * bv[m];
      bc[o] = bb;
    }
  } else {
    int o = b - 128;
    float s = 0.f;
    for (int m = 0; m < 128; m++) s += wo[o * 128 + m] * op_w[m * 128 + c];
    Wcat[o * 256 + c] = bf16rne(s);
    Wcat[o * 256 + 128 + c] = bf16rne(wo[o * 128 + c]);
    if (c == 0) {
      float bb = bo[o];
      for (int m = 0; m < 128; m++) bb += wo[o * 128 + m] * op_b[m];
      cvec[o] = bb;
    }
  }
}

// ---------------- prep: weight conversions + uvec ----------------
__global__ void prepcvt_kernel(const float* __restrict__ qd_w1, const float* __restrict__ qd_w2,
                               const float* __restrict__ off_w, const float* __restrict__ aw_w,
                               const float* __restrict__ off_b, const float* __restrict__ aw_b,
                               const float* __restrict__ rh_w1, const float* __restrict__ rh_w3,
                               const float* __restrict__ wq, const float* __restrict__ rh_w2,
                               u16* Wq1, u16* Wq2, u16* Wmg, float* mgbias, float* w1last,
                               u32* Wh1, u32* Wlog, u32* Wq0, u32* Wcv, float* uvec)
{
  int i = blockIdx.x * NT + threadIdx.x;
  if (i < 16384) {
    int r = i >> 7, c = i & 127;
    Wq1[i] = bf16rne(qd_w1[r * 129 + c]);
    Wq2[i] = bf16rne(qd_w2[i]);
  }
  if (i < 20480) {
    int r = i >> 7, c = i & 127;
    float v = (r < 96) ? off_w[r * 128 + c] : ((r < 144) ? aw_w[(r - 96) * 128 + c] : 0.f);
    Wmg[i] = bf16rne(v);
  }
  if (i < 160) mgbias[i] = (i < 96) ? off_b[i] : ((i < 144) ? aw_b[i - 96] : 0.f);
  if (i < 128) w1last[i] = qd_w1[i * 129 + 128];
  if (i < 128 * 96) {
    int r = i / 96, c = i % 96;
    Wh1[i] = packsplit(c < 67 ? rh_w1[r * 67 + c] : 0.f);
  }
  if (i < 112 * 64) {
    int r = i / 64, c = i % 64;
    Wlog[i] = packsplit(r < 110 ? rh_w3[r * 64 + c] : 0.f);
  }
  if (i < 128 * 64) Wq0[i] = packsplit(wq[i]);
  if (i < 9 * 64 * 128) {
    int t = i / (64 * 128), o = (i / 128) % 64, c = i % 128;
    Wcv[i] = packsplit(rh_w2[(o * 128 + c) * 9 + t]);
  }
  if (i < 16384) {
    int hr = i >> 9, w = i & 511;
    float el = c_elev[31 - hr] * 0.017453292519943295f;
    float az = -3.14159265358979323846f + ((float)w + 0.5f) * (6.283185307179586477f / 512.0f);
    float ce = cosf(el);
    uvec[i * 3 + 0] = cosf(az) * ce;
    uvec[i * 3 + 1] = sinf(az) * ce;
    uvec[i * 3 + 2] = sinf(el);
  }
}

// ---------------- GroupNorm stats ----------------
template<int C, int S>
__global__ __launch_bounds__(NT)
void gn_stats_kernel(const float* __restrict__ X, int Npix, float* __restrict__ gs)
{
  constexpr int PPB = NT / C;
  int tid = threadIdx.x;
  int c = tid % C;
  int psub = tid / C;
  float sum = 0.f, ss = 0.f;
  for (long pix = (long)blockIdx.x * PPB + psub; pix < Npix; pix += (long)gridDim.x * PPB) {
    float v = X[pix * C + c];
    sum += v; ss += v * v;
  }
  __shared__ float ls[8][2];
  if (tid < 16) ls[tid / 2][tid % 2] = 0.f;
  __syncthreads();
  int g = c / S;
  atomicAdd(&ls[g][0], sum);
  atomicAdd(&ls[g][1], ss);
  __syncthreads();
  if (tid < 16) atomicAdd(&gs[tid], ls[tid / 2][tid % 2]);
}

// ---------------- logits transpose ----------------
__global__ __launch_bounds__(NT)
void tlogits_kernel(const float* __restrict__ logits, float* __restrict__ out1)
{
  __shared__ float ls[128][111];
  int p0 = blockIdx.x * 128;
  for (int i = threadIdx.x; i < 128 * 110; i += NT) {
    int p = i / 110, c = i % 110;
    ls[p][c] = logits[(long)(p0 + p) * 110 + c];
  }
  __syncthreads();
  for (int i = threadIdx.x; i < 110 * 128; i += NT) {
    int c = i / 128, p = i % 128;
    out1[(long)c * 16384 + p0 + p] = ls[p][c];
  }
}

// ---------------- softmax + top-5 per pixel ----------------
__global__ __launch_bounds__(NT)
void topk_kernel(const float* __restrict__ logits, float* __restrict__ depths,
                 float* __restrict__ wgt)
{
  int lane = threadIdx.x & 63;
  int pix = (blockIdx.x * NT + threadIdx.x) >> 6;
  const float* lr = logits + (long)pix * 110;
  float v0 = (lane < 110) ? lr[lane] : -1e30f;
  float v1 = (lane + 64 < 110) ? lr[lane + 64] : -1e30f;
  float m = fmaxf(v0, v1);
#pragma unroll
  for (int s = 32; s; s >>= 1) m = fmaxf(m, __shfl_xor(m, s));
  float ex = ((lane < 110) ? expf(v0 - m) : 0.f) + ((lane + 64 < 110) ? expf(v1 - m) : 0.f);
  float den = ex;
#pragma unroll
  for (int s = 32; s; s >>= 1) den += __shfl_xor(den, s);
  float pr[5]; int pi[5];
#pragma unroll
  for (int j = 0; j < 5; j++) {
    float bv; int bi;
    if (v0 >= v1) { bv = v0; bi = lane; } else { bv = v1; bi = lane + 64; }
    for (int s = 1; s < 64; s <<= 1) {
      float ov = __shfl_xor(bv, s);
      int oi = __shfl_xor(bi, s);
      if (ov > bv || (ov == bv && oi < bi)) { bv = ov; bi = oi; }
    }
    pr[j] = expf(bv - m) / den;
    pi[j] = bi;
    if (bi == lane) v0 = -1e30f;
    if (bi == lane + 64) v1 = -1e30f;
  }
  if (lane == 0) {
    float tot = pr[0] + pr[1] + pr[2] + pr[3] + pr[4] + 1e-8f;
#pragma unroll
    for (int j = 0; j < 5; j++) {
      depths[pix * 5 + j] = fminf(0.5f * ((float)pi[j] + 0.5f), 54.75f);
      wgt[pix * 5 + j] = pr[j] / tot;
    }
  }
}

// ---------------- deformable sampling: k-major, 8 ch/thread, refq inline ----------------
__global__ __launch_bounds__(NT)
void msda_kernel(const u16* __restrict__ V, const float* __restrict__ depths,
                 const float* __restrict__ uvec, const float* __restrict__ L44,
                 const float* __restrict__ offb, const u16* __restrict__ awb,
                 u16* __restrict__ S)
{
  const int tid = threadIdx.x;
  const int kk = blockIdx.x >> 10;           // depth slot 0..4
  const int pg = blockIdx.x & 1023;
  const long pix = (long)pg * 16 + (tid >> 4);
  const int h = (tid >> 1) & 7;
  const int c0 = h * 16 + (tid & 1) * 8;
  const long q = pix * 5 + kk;

  // reference point (refq folded in)
  float d = depths[q];
  float ux = uvec[pix * 3 + 0], uy = uvec[pix * 3 + 1], uz = uvec[pix * 3 + 2];
  float px = d * ux, py = d * uy, pz = d * uz;
  float pex = px * L44[0] + py * L44[4] + pz * L44[8] + L44[12];
  float pey = px * L44[1] + py * L44[5] + pz * L44[9] + L44[13];
  float rx = fminf(fmaxf((pex + 55.0f) * (1.0f / 110.0f), 0.f), 1.f);
  float ry = fminf(fmaxf((pey + 55.0f) * (1.0f / 110.0f), 0.f), 1.f);
  float rxs = rx * 256.0f - 0.5f;
  float rys = ry * 256.0f - 0.5f;

  // attention softmax
  const u32* ap32 = (const u32*)(awb + q * 48 + h * 6);
  u32 aw0 = ap32[0], aw1 = ap32[1], aw2 = ap32[2];
  float a[6] = { bflo(aw0), bfhi(aw0), bflo(aw1), bfhi(aw1), bflo(aw2), bfhi(aw2) };
  float mx = fmaxf(fmaxf(fmaxf(a[0], a[1]), fmaxf(a[2], a[3])), fmaxf(a[4], a[5]));
  float se = 0.f;
#pragma unroll
  for (int p = 0; p < 6; p++) { a[p] = __expf(a[p] - mx); se += a[p]; }
  const float inv = 1.0f / se;

  const f32x4* opv = (const f32x4*)(offb + q * 96 + h * 12);
  f32x4 of0 = opv[0], of1 = opv[1], of2 = opv[2];
  const float ox[6] = { of0[0], of0[2], of1[0], of1[2], of2[0], of2[2] };
  const float oy[6] = { of0[1], of0[3], of1[1], of1[3], of2[1], of2[3] };

  float acc[8];
#pragma unroll
  for (int j = 0; j < 8; j++) acc[j] = 0.f;

#pragma unroll
  for (int p = 0; p < 6; p++) {
    float x = rxs + ox[p];
    float y = rys + oy[p];
    float x0f = floorf(x), y0f = floorf(y);
    float wx = x - x0f, wy = y - y0f;
    int ix = (int)x0f, iy = (int)y0f;
    float awp = a[p] * inv;
    float wx0 = ((unsigned)ix < 256u) ? (1.f - wx) : 0.f;
    float wx1 = ((unsigned)(ix + 1) < 256u) ? wx : 0.f;
    float wy0 = ((unsigned)iy < 256u) ? (awp * (1.f - wy)) : 0.f;
    float wy1 = ((unsigned)(iy + 1) < 256u) ? (awp * wy) : 0.f;
    int xc0 = min(max(ix, 0), 255), xc1 = min(max(ix + 1, 0), 255);
    int yc0 = min(max(iy, 0), 255), yc1 = min(max(iy + 1, 0), 255);
#pragma unroll
    for (int cy = 0; cy < 2; cy++) {
      int yb = (cy ? yc1 : yc0) << 15;
      float wyv = cy ? wy1 : wy0;
#pragma unroll
      for (int cx = 0; cx < 2; cx++) {
        int idx = yb + ((cx ? xc1 : xc0) << 7) + c0;
        float m = (cx ? wx1 : wx0) * wyv;
        u32x4 v = *(const u32x4*)(V + idx);
#pragma unroll
        for (int e = 0; e < 4; e++) {
          acc[2 * e]     += m * bflo(v[e]);
          acc[2 * e + 1] += m * bfhi(v[e]);
        }
      }
    }
  }
  u32x4 o;
#pragma unroll
  for (int e = 0; e < 4; e++)
    o[e] = (u32)bf16rne(acc[2 * e]) | ((u32)bf16rne(acc[2 * e + 1]) << 16);
  *(u32x4*)(S + q * 128 + c0) = o;
}

} // namespace

extern "C" void kernel_launch(void* const* d_in, const int* in_sizes, int n_in,
                              void* d_out, int out_size, void* d_ws, size_t ws_size,
                              hipStream_t stream)
{
  (void)in_sizes; (void)n_in; (void)out_size; (void)ws_size;
  const float* x_rv   = (const float*)d_in[0];
  const float* bev    = (const float*)d_in[1];
  const float* L44    = (const float*)d_in[2];
  const float* wq     = (const float*)d_in[3];
  const float* bq     = (const float*)d_in[4];
  const float* wv     = (const float*)d_in[5];
  const float* bv     = (const float*)d_in[6];
  const float* woW    = (const float*)d_in[7];
  const float* boB    = (const float*)d_in[8];
  const float* qd_w1  = (const float*)d_in[9];
  const float* qd_b1  = (const float*)d_in[10];
  const float* qd_w2  = (const float*)d_in[11];
  const float* qd_b2  = (const float*)d_in[12];
  const float* rh_w1  = (const float*)d_in[13];
  const float* rh_b1  = (const float*)d_in[14];
  const float* rh_g1  = (const float*)d_in[15];
  const float* rh_be1 = (const float*)d_in[16];
  const float* rh_w2  = (const float*)d_in[17];
  const float* rh_g2  = (const float*)d_in[18];
  const float* rh_be2 = (const float*)d_in[19];
  const float* rh_w3  = (const float*)d_in[20];
  const float* rh_b3  = (const float*)d_in[21];
  const float* off_w  = (const float*)d_in[22];
  const float* off_b  = (const float*)d_in[23];
  const float* aw_w   = (const float*)d_in[24];
  const float* aw_b   = (const float*)d_in[25];
  const float* vp_w   = (const float*)d_in[26];
  const float* vp_b   = (const float*)d_in[27];
  const float* op_w   = (const float*)d_in[28];
  const float* op_b   = (const float*)d_in[29];

  float* outY = (float*)d_out;
  float* outL = (float*)d_out + 2097152;

  char* wsb = (char*)d_ws;
  size_t off = 0;
  auto alloc = [&](size_t bytes) -> char* {
    char* p = wsb + off;
    off += (bytes + 255) & ~(size_t)255;
    return p;
  };

  u16*   wcomb  = (u16*)alloc(32768);
  float* bcomb  = (float*)alloc(512);
  float* uvec   = (float*)alloc(196608);
  float* stats  = (float*)alloc(128);
  float* depths = (float*)alloc(327680);
  float* wgtb   = (float*)alloc(327680);
  float* w1last = (float*)alloc(512);
  u16*   Wq1    = (u16*)alloc(32768);
  u16*   Wq2    = (u16*)alloc(32768);
  u16*   Wmg    = (u16*)alloc(40960);
  float* mgbias = (float*)alloc(640);
  u16*   Wcat   = (u16*)alloc(65536);
  float* cvec   = (float*)alloc(512);
  u32*   Wh1    = (u32*)alloc(49152);
  u32*   Wlog   = (u32*)alloc(28672);
  u32*   Wq0    = (u32*)alloc(32768);
  u32*   Wcv    = (u32*)alloc(294912);
  char*  S1     = alloc(20971520);   // h1|logits|h2 -> smp
  char*  S2     = alloc(4194304);    // Q0 bf16
  char*  S3     = alloc(16777216);   // v bf16
  char*  S5     = alloc(20971520);   // query bf16
  float* offbuf = (float*)alloc(31457280);
  u16*   awbf   = (u16*)alloc(7864320);

  float* h1buf  = (float*)S1;                   // [16384][128] raw (GN folded downstream)
  float* logits = (float*)(S1 + 8388608);       // [16384][110]
  float* h2buf  = (float*)(S1 + 15597568);      // [16384][64] raw
  u16*   smp    = (u16*)S1;                     // [81920][128] (depth head dead)
  u16*   Q0bf   = (u16*)S2;
  u16*   vbuf   = (u16*)S3;
  u16*   querybf= (u16*)S5;

  float* stats1 = stats;
  float* stats2 = stats + 16;

  hipMemsetAsync((void*)stats, 0, 128, stream);

  // weight prep (merged)
  prepmm_kernel<<<256, 128, 0, stream>>>(vp_w, wv, vp_b, bv, woW, op_w, op_b, boB,
                                         wcomb, bcomb, Wcat, cvec);
  prepcvt_kernel<<<288, NT, 0, stream>>>(qd_w1, qd_w2, off_w, aw_w, off_b, aw_b,
                                         rh_w1, rh_w3, wq, rh_w2,
                                         Wq1, Wq2, Wmg, mgbias, w1last,
                                         Wh1, Wlog, Wq0, Wcv, uvec);

  // Q0 = x_rv @ wq^T + bq  (single-f16 MFMA, bf16 out)
  slin<128, 128, 64, 64, 1, 0, false, true><<<256, NT, 0, stream>>>(
      x_rv, nullptr, Wq0, bq, nullptr, nullptr, nullptr, nullptr, Q0bf);

  // depth head: h1 raw, GN1 applied at conv staging, GN2 at logits staging
  slin<128, 128, 96, 67, 3, 1, false, false><<<256, NT, 0, stream>>>(
      x_rv, uvec, Wh1, rh_b1, nullptr, nullptr, nullptr, h1buf, nullptr);
  gn_stats_kernel<128, 16><<<512, NT, 0, stream>>>(h1buf, 16384, stats1);
  conv_mfma<<<512, NT, 0, stream>>>(h1buf, Wcv, stats1, rh_g1, rh_be1, h2buf);
  gn_stats_kernel<64, 8><<<512, NT, 0, stream>>>(h2buf, 16384, stats2);
  slin<110, 112, 64, 64, 3, 0, false, false, true><<<256, NT, 0, stream>>>(
      h2buf, nullptr, Wlog, rh_b3, stats2, rh_g2, rh_be2, logits, nullptr);
  tlogits_kernel<<<128, NT, 0, stream>>>(logits, outL);
  topk_kernel<<<4096, NT, 0, stream>>>(logits, depths, wgtb);

  // v = bev(NCHW) @ (vp_w . wv)^T + bias -> bf16 [65536][128]
  mfma_lin<128, 4, false, false, false, true, false><<<1024, NT, 0, stream>>>(
      bev, nullptr, wcomb, bcomb, nullptr, nullptr, vbuf, 65536);

  // fused query MLP
  qmlp_kernel<<<1280, NT, 0, stream>>>(Q0bf, depths, Wq1, qd_b1, w1last, Wq2, qd_b2, querybf);

  // merged offsets (f32) + attention logits (bf16), CO=160
  mfma_lin<160, 0, false, false, false, false, true><<<1280, NT, 0, stream>>>(
      querybf, nullptr, Wmg, mgbias, nullptr, offbuf, awbf, 0);

  // deformable sampling (8 ch/thread, refq inline)
  msda_kernel<<<5120, NT, 0, stream>>>(vbuf, depths, uvec, L44, offbuf, awbf, smp);

  // fused combine + output projection
  outproj_kernel<<<256, NT, 0, stream>>>(smp, querybf, wgtb, Wcat, cvec, outY);
}